// Round 6
// baseline (383.435 us; speedup 1.0000x reference)
//
#include <hip/hip_runtime.h>

#define NN 8192
#define FIN 128
#define FOUT 64
#define NSLICE 4
#define JSLICE (NN / NSLICE)
#define JTILE 256
#define NT (JSLICE / JTILE)   // 8 tiles per block
#define PT_LD 264             // Pt row stride in shorts: 256 + 8 pad

typedef __attribute__((ext_vector_type(8))) short short8;
typedef __attribute__((ext_vector_type(4))) float floatx4;
typedef __attribute__((ext_vector_type(4))) unsigned short ushort4v;

__device__ __forceinline__ unsigned short f32_to_bf16(float f) {
    unsigned int u = __float_as_uint(f);
    return (unsigned short)((u + 0x7FFFu + ((u >> 16) & 1u)) >> 16);
}
__device__ __forceinline__ float bf16_to_f32(unsigned short b) {
    return __uint_as_float(((unsigned int)b) << 16);
}

// Async global->LDS: 64 lanes x 16B = 1 KB per call; LDS dest = uniform base + lane*16.
#define GLD_LDS16(g, l) __builtin_amdgcn_global_load_lds( \
    (__attribute__((address_space(1))) const unsigned int*)(g), \
    (__attribute__((address_space(3))) unsigned int*)(l), 16, 0, 0)

// Kernel 1: wh = h @ W (fp32). Writes whB directly in MFMA B-fragment order
// (bf16), plus src[i] = wh[i].a1 + edge[i]*(wedge.a3), dst[i] = wh[i].a2.
__global__ __launch_bounds__(256) void gat_prep(
    const float* __restrict__ h,      // 8192x128
    const float* __restrict__ edge,   // 8192x1
    const float* __restrict__ weight, // 128x64
    const float* __restrict__ att,    // 192x1
    const float* __restrict__ wedge,  // 1x64
    unsigned short* __restrict__ whB, // bf16 fragment-order (1 MB)
    float* __restrict__ src,          // 8192
    float* __restrict__ dst)          // 8192
{
    __shared__ float wl[FIN * FOUT];   // 32 KB
    __shared__ float hl[16 * FIN];     // 8 KB
    const int tid = threadIdx.x;
    const int b = blockIdx.x;

    const float4* w4 = (const float4*)weight;
    float4* wl4 = (float4*)wl;
    for (int idx = tid; idx < FIN * FOUT / 4; idx += 256) wl4[idx] = w4[idx];
    const float4* h4 = (const float4*)(h + (size_t)b * 16 * FIN);
    float4* hl4 = (float4*)hl;
    for (int idx = tid; idx < 16 * FIN / 4; idx += 256) hl4[idx] = h4[idx];
    __syncthreads();

    const int wave = tid >> 6;
    const int lane = tid & 63;
    float acc[4] = {0.f, 0.f, 0.f, 0.f};
    for (int c = 0; c < FIN; ++c) {
        const float wv = wl[c * FOUT + lane];
#pragma unroll
        for (int r = 0; r < 4; ++r)
            acc[r] = fmaf(hl[(wave * 4 + r) * FIN + c], wv, acc[r]);
    }
    const int row0 = b * 16 + wave * 4;

    // whB fragment-order store (layout verified r3-r5)
    {
        const int T = b >> 2;
        const int o = (b & 3) * 16 + wave * 4;
        const int c = o >> 5;
        const int quad = (o >> 3) & 3;
        const int i0 = o & 7;
        const int q = lane >> 4, col = lane & 15;
        const int f = T * 8 + q * 2 + c;
        const int elem = f * 64 + quad * 16 + col;
        ushort4v wb;
#pragma unroll
        for (int r = 0; r < 4; ++r) wb[r] = f32_to_bf16(acc[r]);
        *(ushort4v*)(whB + (size_t)elem * 8 + i0) = wb;
    }

    const float a1 = att[lane];
    const float a2 = att[FOUT + lane];
    float t3 = wedge[lane] * att[2 * FOUT + lane];
#pragma unroll
    for (int off = 32; off > 0; off >>= 1) t3 += __shfl_xor(t3, off, 64);

#pragma unroll
    for (int r = 0; r < 4; ++r) {
        float t1 = acc[r] * a1;
        float t2 = acc[r] * a2;
#pragma unroll
        for (int off = 32; off > 0; off >>= 1) {
            t1 += __shfl_xor(t1, off, 64);
            t2 += __shfl_xor(t2, off, 64);
        }
        if (lane == 0) {
            src[row0 + r] = t1 + edge[row0 + r] * t3;
            dst[row0 + r] = t2;
        }
    }
}

// Kernel 2: fused masked-softmax-numerator + P@Wh via MFMA.
// adj staged via async global_load_lds (double-buffered, 4 KB/wave in flight,
// zero VGPR cost); adjT rows are wave-private so arrival needs only a
// vmcnt(0)-only wait, no barrier. dst slice staged in LDS once. Pt is
// single-buffered with two lgkm-only raw barriers (no vmcnt drain). Next-tile
// adj issue is placed AFTER the whB loads so compiler per-MFMA vmcnt waits
// leave the adj prefetch in flight (sched_barrier pins the order).
__global__ __launch_bounds__(256) void gat_attn(
    const int* __restrict__ adj,
    const unsigned short* __restrict__ whB,
    const float* __restrict__ src,
    const float* __restrict__ dst,
    float* __restrict__ ws_acc,      // [4][8192][64]
    float* __restrict__ ws_l)        // [4][8192]
{
    __shared__ int adjT[2][16][JTILE];            // 32 KB
    __shared__ unsigned short Pt[16][PT_LD];      // 8.4 KB
    __shared__ float dstL[JSLICE];                // 8 KB
    const int wave = threadIdx.x >> 6;
    const int lane = threadIdx.x & 63;
    const int i0 = blockIdx.x * 16;
    const int s  = blockIdx.y;
    const size_t jbase = (size_t)s * JSLICE;
    const int m = lane & 15, quad = lane >> 4;

    // Stage dst slice into LDS
    {
        const float4* dg = (const float4*)(dst + jbase);
        float4* dl4 = (float4*)dstL;
        for (int idx = threadIdx.x; idx < JSLICE / 4; idx += 256) dl4[idx] = dg[idx];
    }

    float sr[4];
    const int* ap[4];
#pragma unroll
    for (int r = 0; r < 4; ++r) {
        sr[r] = src[i0 + wave * 4 + r];
        ap[r] = adj + (size_t)(i0 + wave * 4 + r) * NN + jbase;
    }
    float lsum[4] = {0.f, 0.f, 0.f, 0.f};
    floatx4 acc = {0.f, 0.f, 0.f, 0.f};

    __syncthreads();   // dstL visible; vmcnt drained

    // Prologue: issue adj tile 0 (wave-private rows)
#pragma unroll
    for (int r = 0; r < 4; ++r)
        GLD_LDS16(ap[r] + lane * 4, &adjT[0][wave * 4 + r][0]);

    for (int t = 0; t < NT; ++t) {
        const int buf = t & 1;

        // [A] my tile-t adj rows have landed in LDS (vmcnt-only wait)
        __builtin_amdgcn_s_waitcnt(0x0F70);      // vmcnt(0), lgkm/exp unbounded
        __builtin_amdgcn_sched_barrier(0);

        // Phase 1: read adjT + dstL, exp-compute, pack bf16
        int4 av[4];
#pragma unroll
        for (int r = 0; r < 4; ++r)
            av[r] = *(const int4*)&adjT[buf][wave * 4 + r][lane * 4];
        const float4 dv = *(const float4*)&dstL[t * JTILE + lane * 4];
        ushort4v pv[4];
#pragma unroll
        for (int r = 0; r < 4; ++r) {
            float v, p;
            v = sr[r] + dv.x; v = fmaxf(v, 0.2f * v);
            p = (av[r].x > 0) ? __expf(v) : 0.f; pv[r].x = f32_to_bf16(p);
            v = sr[r] + dv.y; v = fmaxf(v, 0.2f * v);
            p = (av[r].y > 0) ? __expf(v) : 0.f; pv[r].y = f32_to_bf16(p);
            v = sr[r] + dv.z; v = fmaxf(v, 0.2f * v);
            p = (av[r].z > 0) ? __expf(v) : 0.f; pv[r].z = f32_to_bf16(p);
            v = sr[r] + dv.w; v = fmaxf(v, 0.2f * v);
            p = (av[r].w > 0) ? __expf(v) : 0.f; pv[r].w = f32_to_bf16(p);
            lsum[r] += bf16_to_f32(pv[r].x) + bf16_to_f32(pv[r].y)
                     + bf16_to_f32(pv[r].z) + bf16_to_f32(pv[r].w);
        }

        // Barrier #1: all waves finished reading Pt in MFMA(t-1)
        __builtin_amdgcn_sched_barrier(0);
        __builtin_amdgcn_s_barrier();
        __builtin_amdgcn_sched_barrier(0);

#pragma unroll
        for (int r = 0; r < 4; ++r)
            *(ushort4v*)&Pt[wave * 4 + r][4 * lane] = pv[r];

        // Barrier #2: Pt visible to all waves (lgkm-only; adj stays in flight)
        __builtin_amdgcn_s_waitcnt(0xC07F);      // lgkmcnt(0)
        __builtin_amdgcn_s_barrier();
        __builtin_amdgcn_sched_barrier(0);

        // whB B-fragments for this tile (L2-resident, coalesced 16B/lane)
        const int jt0 = (int)((jbase + (size_t)t * JTILE) >> 6);
        short8 bfr[8];
#pragma unroll
        for (int kk = 0; kk < 8; ++kk) {
            const int f = (jt0 + (kk >> 1)) * 8 + wave * 2 + (kk & 1);
            bfr[kk] = *((const short8*)whB + (size_t)f * 64 + lane);
        }
        __builtin_amdgcn_sched_barrier(0);

        // Issue next tile's adj AFTER whB loads: per-MFMA vmcnt waits for bfr
        // resolve without draining these 4 loads.
        if (t + 1 < NT) {
#pragma unroll
            for (int r = 0; r < 4; ++r)
                GLD_LDS16(ap[r] + (t + 1) * JTILE + lane * 4,
                          &adjT[(t + 1) & 1][wave * 4 + r][0]);
        }
        __builtin_amdgcn_sched_barrier(0);

        // 8 MFMAs over K=256
#pragma unroll
        for (int kk = 0; kk < 8; ++kk) {
            const short8 a = *(const short8*)&Pt[m][kk * 32 + quad * 8];
            acc = __builtin_amdgcn_mfma_f32_16x16x32_bf16(a, bfr[kk], acc, 0, 0, 0);
        }
    }

#pragma unroll
    for (int r = 0; r < 4; ++r) {
#pragma unroll
        for (int off = 32; off > 0; off >>= 1)
            lsum[r] += __shfl_xor(lsum[r], off, 64);
    }
    if (lane == 0) {
#pragma unroll
        for (int r = 0; r < 4; ++r)
            ws_l[(size_t)s * NN + i0 + wave * 4 + r] = lsum[r];
    }

    // C/D layout: col = lane&15, row = quad*4 + reg
#pragma unroll
    for (int reg = 0; reg < 4; ++reg) {
        const int row = quad * 4 + reg;
        ws_acc[(size_t)s * (NN * FOUT) + (size_t)(i0 + row) * FOUT + wave * 16 + m] = acc[reg];
    }
}

// Kernel 3: reduce 4 j-slices, divide by softmax denom, ELU.
__global__ __launch_bounds__(256) void gat_finish(
    const float* __restrict__ ws_acc, const float* __restrict__ ws_l,
    float* __restrict__ out)
{
    const int idx = blockIdx.x * 256 + threadIdx.x;   // 0 .. 8192*64-1
    const int i = idx >> 6;
    float a = 0.f, l = 0.f;
#pragma unroll
    for (int s = 0; s < NSLICE; ++s) {
        a += ws_acc[(size_t)s * (NN * FOUT) + idx];
        l += ws_l[(size_t)s * NN + i];
    }
    float v = a / l;
    out[idx] = (v > 0.f) ? v : expm1f(v);
}

extern "C" void kernel_launch(void* const* d_in, const int* in_sizes, int n_in,
                              void* d_out, int out_size, void* d_ws, size_t ws_size,
                              hipStream_t stream) {
    const float* h      = (const float*)d_in[0];
    const float* edge   = (const float*)d_in[1];
    const int*   adj    = (const int*)d_in[2];
    const float* weight = (const float*)d_in[3];
    const float* att    = (const float*)d_in[4];
    const float* wedge  = (const float*)d_in[5];
    float* out = (float*)d_out;

    unsigned short* whB = (unsigned short*)d_ws;          // 1 MB bf16 frags
    float* src    = (float*)(whB + (size_t)NN * FOUT);    // 8192
    float* dst    = src + NN;                             // 8192
    float* ws_l   = dst + NN;                             // 4*8192
    float* ws_acc = ws_l + (size_t)NSLICE * NN;           // 8 MB

    gat_prep<<<NN / 16, 256, 0, stream>>>(h, edge, weight, att, wedge, whB, src, dst);
    gat_attn<<<dim3(NN / 16, NSLICE), 256, 0, stream>>>(adj, whB, src, dst, ws_acc, ws_l);
    gat_finish<<<NN * FOUT / 256, 256, 0, stream>>>(ws_acc, ws_l, out);
}